// Round 10
// baseline (340.105 us; speedup 1.0000x reference)
//
#include <hip/hip_runtime.h>

// CapsuleFC: B=64, N=128, A=64, M=128, D=64
// out = [ncv (B*M*D) | na (B*M) | qk (B*N*M)], fp32
// ROUND 10: real path = verified 161us legacy pipeline. Two DUMMY diagnostic
// dispatches (k_conv3 + 2x-repeat k1_logits2 into scratch) appended to measure
// the converter and the contiguous-DMA consumer directly via top-5 visibility.
typedef __attribute__((ext_vector_type(8))) short bf16x8;
typedef __attribute__((ext_vector_type(4))) float f32x4;

constexpr int Bq = 64, Nq = 128, Aq = 64, Mq = 128, Dq = 64;
constexpr int MD = Mq * Dq;    // 8192
constexpr int NM = Nq * Mq;    // 16384
constexpr int NA = Nq * Aq;    // 8192
constexpr int NCV_SZ = Bq * MD;   // 524288
constexpr int NA_SZ  = Bq * Mq;   // 8192
constexpr float SCALE = 0.125f;   // 1/sqrt(64)
constexpr size_t W2_BYTES   = (size_t)32 * 128 * 2 * 16384;   // 128 MiB
constexpr size_t DIAG_BYTES = (size_t)512 * 1024 * 1024;      // need 512 MiB ws

__device__ __forceinline__ unsigned short f2b(float f) {  // fp32 -> bf16 RNE
  unsigned u = __float_as_uint(f);
  return (unsigned short)((u + 0x7fffu + ((u >> 16) & 1u)) >> 16);
}
__device__ __forceinline__ unsigned cvt2(float lo, float hi) {
  return ((unsigned)f2b(hi) << 16) | (unsigned)f2b(lo);
}
__device__ __forceinline__ bf16x8 pack8(const float* v) {
  union { unsigned u[4]; bf16x8 b; } x;
  x.u[0] = cvt2(v[0], v[1]); x.u[1] = cvt2(v[2], v[3]);
  x.u[2] = cvt2(v[4], v[5]); x.u[3] = cvt2(v[6], v[7]);
  return x.b;
}
__device__ __forceinline__ void dma16(const float* g, float* l) {
  __builtin_amdgcn_global_load_lds(
      (const __attribute__((address_space(1))) unsigned*)g,
      (__attribute__((address_space(3))) unsigned*)l, 16, 0, 0);
}
__device__ __forceinline__ void dma16c(const char* g, void* l) {
  __builtin_amdgcn_global_load_lds(
      (const __attribute__((address_space(1))) unsigned*)g,
      (__attribute__((address_space(3))) unsigned*)l, 16, 0, 0);
}

// ---------------- init: ncv = 0, na = 1 ----------------
__global__ __launch_bounds__(256) void k0_init(float* __restrict__ out) {
  int i = blockIdx.x * 256 + threadIdx.x;
  if (i < NCV_SZ) out[i] = 0.0f;
  else if (i < NCV_SZ + NA_SZ) out[i] = 1.0f;
}

// ---------------- K1 (legacy, verified ~110us): logits via MFMA ----------------
__global__ __launch_bounds__(256, 2) void k1_logits(
    const float* __restrict__ input, const float* __restrict__ ncvin,
    const float* __restrict__ wgt, float* __restrict__ logits) {
  const int mc = blockIdx.x;
  const int n0 = blockIdx.y * 8;
  const int t = threadIdx.x;
  const int wv = t >> 6, l = t & 63;
  const int lr = l & 15, g = l >> 4;
  const int m = mc * 4 + wv;
  __shared__ float Wf[2][32 * 256];
  float cnv[4][4][4];
#pragma unroll
  for (int i = 0; i < 4; ++i)
#pragma unroll
    for (int j = 0; j < 4; ++j)
#pragma unroll
      for (int r = 0; r < 4; ++r)
        cnv[i][j][r] = ncvin[(size_t)(16 * i + 4 * g + r) * MD + m * Dq + 16 * j + lr];
  auto stage = [&](int h) {
    const int hh = 15 - h;
    const int nn = n0 + (hh >> 1);
    const int ks = (hh & 1) * 32;
    float* dst = &Wf[h & 1][0];
#pragma unroll
    for (int rr = 0; rr < 8; ++rr) {
      const int al = wv * 8 + rr;
      const char* gs = (const char*)(wgt + (size_t)(nn * Aq + ks + al) * MD + mc * 256)
                       + ((l * 16) ^ (((al >> 3) & 1) << 6));
      dma16((const float*)gs, dst + al * 256);
    }
  };
  stage(0);
  f32x4 acc[4][4];
  for (int h = 0; h < 16; ++h) {
    const int hh = 15 - h;
    const int nn = n0 + (hh >> 1);
    const int ks = (hh & 1) * 32;
    float av[4][8];
#pragma unroll
    for (int i = 0; i < 4; ++i) {
      const float* ap = input + (size_t)(16 * i + lr) * NA + nn * Aq + ks + g * 8;
      *(float4*)&av[i][0] = *(const float4*)ap;
      *(float4*)&av[i][4] = *(const float4*)(ap + 4);
    }
    __builtin_amdgcn_sched_barrier(0);
    if (h < 15) { stage(h + 1); asm volatile("s_waitcnt vmcnt(8)" ::: "memory"); }
    else { asm volatile("s_waitcnt vmcnt(0)" ::: "memory"); }
    __builtin_amdgcn_s_barrier();
    if ((h & 1) == 0) {
#pragma unroll
      for (int i = 0; i < 4; ++i)
#pragma unroll
        for (int j = 0; j < 4; ++j) acc[i][j] = (f32x4)(0.0f);
    }
    bf16x8 af[4];
#pragma unroll
    for (int i = 0; i < 4; ++i) af[i] = pack8(av[i]);
    const float* bufp = &Wf[h & 1][0];
#pragma unroll
    for (int j = 0; j < 4; ++j) {
      const int cx = (64 * wv + 16 * j + lr) ^ ((g & 1) << 4);
      float bv[8];
#pragma unroll
      for (int e = 0; e < 8; ++e) bv[e] = bufp[(g * 8 + e) * 256 + cx];
      bf16x8 bf = pack8(bv);
#pragma unroll
      for (int i = 0; i < 4; ++i)
        acc[i][j] = __builtin_amdgcn_mfma_f32_16x16x32_bf16(af[i], bf, acc[i][j], 0, 0, 0);
    }
    __builtin_amdgcn_s_barrier();
    if (h & 1) {
      float lp[4][4];
#pragma unroll
      for (int i = 0; i < 4; ++i)
#pragma unroll
        for (int r = 0; r < 4; ++r) lp[i][r] = 0.0f;
#pragma unroll
      for (int i = 0; i < 4; ++i)
#pragma unroll
        for (int j = 0; j < 4; ++j)
#pragma unroll
          for (int r = 0; r < 4; ++r)
            lp[i][r] = fmaf(acc[i][j][r], cnv[i][j][r], lp[i][r]);
#pragma unroll
      for (int off = 1; off < 16; off <<= 1)
#pragma unroll
        for (int i = 0; i < 4; ++i)
#pragma unroll
          for (int r = 0; r < 4; ++r) lp[i][r] += __shfl_xor(lp[i][r], off);
      float ov = lp[0][0];
#pragma unroll
      for (int i = 0; i < 4; ++i)
#pragma unroll
        for (int r = 0; r < 4; ++r)
          ov = (lr == i * 4 + r) ? lp[i][r] : ov;
      const int b = 16 * (lr >> 2) + 4 * g + (lr & 3);
      logits[(size_t)b * NM + (size_t)nn * Mq + m] = SCALE * ov;
    }
  }
}

// ---------------- K2: softmax + act modulation + renorm (in place) ----------------
__global__ __launch_bounds__(256) void k2_softmax(
    const float* __restrict__ next_act, float* __restrict__ qk) {
  const int row  = blockIdx.x * 4 + (threadIdx.x >> 6);
  const int lane = threadIdx.x & 63;
  const int b = row >> 7;
  float* p = qk + (size_t)row * Mq;
  float x0 = p[lane], x1 = p[lane + 64];
  float mx = fmaxf(x0, x1);
#pragma unroll
  for (int off = 32; off; off >>= 1) mx = fmaxf(mx, __shfl_xor(mx, off));
  float e0 = __expf(x0 - mx), e1 = __expf(x1 - mx);
  float s = e0 + e1;
#pragma unroll
  for (int off = 32; off; off >>= 1) s += __shfl_xor(s, off);
  float a0 = next_act[b * Mq + lane], a1 = next_act[b * Mq + lane + 64];
  float t0 = (e0 / s) * a0, t1 = (e1 / s) * a1;
  float s2 = t0 + t1;
#pragma unroll
  for (int off = 32; off; off >>= 1) s2 += __shfl_xor(s2, off);
  s2 += 1e-10f;
  p[lane]      = t0 / s2;
  p[lane + 64] = t1 / s2;
}

// ---------------- K3 (legacy, verified ~30us): aggregation via MFMA ----------------
__global__ __launch_bounds__(256, 2) void k3_aggregate(
    const float* __restrict__ input, const float* __restrict__ cur_act,
    const float* __restrict__ wgt, const float* __restrict__ qk,
    float* __restrict__ ncv) {
  const int mc = blockIdx.x;
  const int n0 = blockIdx.y * 8;
  const int t = threadIdx.x;
  const int wv = t >> 6, l = t & 63;
  const int lr = l & 15, g = l >> 4;
  const int m = mc * 4 + wv;
  __shared__ float Wf[2][32 * 256];
  __shared__ float zl[8][4][64];
#pragma unroll
  for (int p = 0; p < 2; ++p) {
    const int idx = t + p * 256;
    const int b = idx >> 3, nn = idx & 7;
    float4 q4 = *(const float4*)&qk[(size_t)b * NM + (size_t)(n0 + nn) * Mq + mc * 4];
    float ca = cur_act[b * Nq + n0 + nn];
    zl[nn][0][b] = q4.x * ca; zl[nn][1][b] = q4.y * ca;
    zl[nn][2][b] = q4.z * ca; zl[nn][3][b] = q4.w * ca;
  }
  __syncthreads();
  auto stage = [&](int h) {
    const int nn = n0 + (h >> 1);
    const int ks = (h & 1) * 32;
    float* dst = &Wf[h & 1][0];
#pragma unroll
    for (int rr = 0; rr < 8; ++rr) {
      const int al = wv * 8 + rr;
      const char* gs = (const char*)(wgt + (size_t)(nn * Aq + ks + al) * MD + mc * 256)
                       + ((l * 16) ^ (((al >> 3) & 1) << 6));
      dma16((const float*)gs, dst + al * 256);
    }
  };
  stage(0);
  f32x4 acc[4][4];
#pragma unroll
  for (int i = 0; i < 4; ++i)
#pragma unroll
    for (int j = 0; j < 4; ++j) acc[i][j] = (f32x4)(0.0f);
  float zr[4];
  for (int h = 0; h < 16; ++h) {
    const int nnl = h >> 1;
    const int nn = n0 + nnl;
    const int ks = (h & 1) * 32;
    if ((h & 1) == 0) {
#pragma unroll
      for (int i = 0; i < 4; ++i) zr[i] = zl[nnl][wv][16 * i + lr];
    }
    float av[4][8];
#pragma unroll
    for (int i = 0; i < 4; ++i) {
      const float* ap = input + (size_t)(16 * i + lr) * NA + nn * Aq + ks + g * 8;
      *(float4*)&av[i][0] = *(const float4*)ap;
      *(float4*)&av[i][4] = *(const float4*)(ap + 4);
    }
    __builtin_amdgcn_sched_barrier(0);
    if (h < 15) { stage(h + 1); asm volatile("s_waitcnt vmcnt(8)" ::: "memory"); }
    else { asm volatile("s_waitcnt vmcnt(0)" ::: "memory"); }
    __builtin_amdgcn_s_barrier();
    bf16x8 af[4];
#pragma unroll
    for (int i = 0; i < 4; ++i) {
      float sv[8];
#pragma unroll
      for (int e = 0; e < 8; ++e) sv[e] = av[i][e] * zr[i];
      af[i] = pack8(sv);
    }
    const float* bufp = &Wf[h & 1][0];
#pragma unroll
    for (int j = 0; j < 4; ++j) {
      const int cx = (64 * wv + 16 * j + lr) ^ ((g & 1) << 4);
      float bv[8];
#pragma unroll
      for (int e = 0; e < 8; ++e) bv[e] = bufp[(g * 8 + e) * 256 + cx];
      bf16x8 bf = pack8(bv);
#pragma unroll
      for (int i = 0; i < 4; ++i)
        acc[i][j] = __builtin_amdgcn_mfma_f32_16x16x32_bf16(af[i], bf, acc[i][j], 0, 0, 0);
    }
    __builtin_amdgcn_s_barrier();
  }
#pragma unroll
  for (int i = 0; i < 4; ++i)
#pragma unroll
    for (int j = 0; j < 4; ++j) {
      const int d = 16 * j + lr;
#pragma unroll
      for (int r = 0; r < 4; ++r) {
        const int b = 16 * i + 4 * g + r;
        atomicAdd(&ncv[(size_t)b * MD + m * Dq + d], acc[i][j][r]);
      }
    }
}

// ============== DIAGNOSTIC dispatches (write only to d_ws scratch) ==============
// k_conv3: w fp32 -> w2 bf16 tiles; seq reads + lane-linear coalesced writes.
__global__ __launch_bounds__(512) void k_conv3(const float* __restrict__ wgt,
                                               char* __restrict__ w2) {
  const int oct = blockIdx.x, n = blockIdx.y;
  const int ks = oct >> 2, lhi = oct & 3;
  const int a0 = ks * 32 + lhi * 8;
  const int t = threadIdx.x;
  const int l_ = t & 63;
  const float4* base = (const float4*)(wgt + (size_t)(n * 64 + a0) * MD);
  float4 vv[4][8];
#pragma unroll
  for (int ii2 = 0; ii2 < 4; ++ii2)
#pragma unroll
    for (int rr = 0; rr < 8; ++rr)
      vv[ii2][rr] = base[(rr * 4 + ii2) * 512 + t];
  __builtin_amdgcn_sched_barrier(0);
#pragma unroll
  for (int ii2 = 0; ii2 < 4; ++ii2) {
    const int mc = ii2 * 8 + (t >> 6);
    char* tb = w2 + (((size_t)mc * 128 + n) * 2 + ks) * 16384;
#pragma unroll
    for (int cc = 0; cc < 4; ++cc) {
      const int r = lhi * 4 + cc;
      float e8[8];
#pragma unroll
      for (int rr = 0; rr < 8; ++rr) e8[rr] = ((const float*)&vv[ii2][rr])[cc];
      *(bf16x8*)(tb + ((((r * 64) + l_) * 16) ^ ((r & 7) << 4))) = pack8(e8);
    }
  }
}

// k1_dummy: r9's contiguous-DMA consumer, run REP=2 times; output -> scratch.
__global__ __launch_bounds__(256, 2) void k1_dummy(
    const float* __restrict__ input, const float* __restrict__ ncvin,
    const char* __restrict__ w2, float* __restrict__ logits) {
  const int mc = blockIdx.x;
  const int n0 = blockIdx.y * 8;
  const int t = threadIdx.x;
  const int wv = t >> 6, l = t & 63;
  const int lr = l & 15, g = l >> 4;
  const int m = mc * 4 + wv;
  __shared__ uint4 Wl[2][1024];
  float cnv[4][4][4];
#pragma unroll
  for (int i = 0; i < 4; ++i)
#pragma unroll
    for (int j = 0; j < 4; ++j)
#pragma unroll
      for (int r = 0; r < 4; ++r)
        cnv[i][j][r] = ncvin[(size_t)(16 * i + 4 * g + r) * MD + m * Dq + 16 * j + lr];
  auto stage = [&](int h) {
    const int nn = n0 + (h >> 1), ksq = h & 1;
    const char* tile = w2 + (((size_t)mc * 128 + nn) * 2 + ksq) * 16384;
#pragma unroll
    for (int q = 0; q < 4; ++q)
      dma16c(tile + q * 4096 + wv * 1024 + l * 16,
             (char*)&Wl[h & 1][0] + q * 4096 + wv * 1024);
  };
  const int rp = ((l >> 4) << 2) + (l & 3);
  const int sp0 = wv * 16 + ((l & 15) >> 2);
  for (int rep = 0; rep < 2; ++rep) {
    stage(0);
    f32x4 acc[4][4];
    for (int h = 0; h < 16; ++h) {
      const int nn = n0 + (h >> 1), ksq = h & 1;
      float av[4][8];
#pragma unroll
      for (int i = 0; i < 4; ++i) {
        const float* ap = input + (size_t)(16 * i + lr) * NA + nn * Aq + ksq * 32 + g * 8;
        *(float4*)&av[i][0] = *(const float4*)ap;
        *(float4*)&av[i][4] = *(const float4*)(ap + 4);
      }
      __builtin_amdgcn_sched_barrier(0);
      if (h < 15) { stage(h + 1); asm volatile("s_waitcnt vmcnt(4)" ::: "memory"); }
      else { asm volatile("s_waitcnt vmcnt(0)" ::: "memory"); }
      __builtin_amdgcn_s_barrier();
      if (ksq == 0) {
#pragma unroll
        for (int i = 0; i < 4; ++i)
#pragma unroll
          for (int j = 0; j < 4; ++j) acc[i][j] = (f32x4)(0.0f);
      }
      bf16x8 af[4];
#pragma unroll
      for (int i = 0; i < 4; ++i) af[i] = pack8(av[i]);
      const char* tilel = (const char*)&Wl[h & 1][0];
#pragma unroll
      for (int j = 0; j < 4; ++j) {
        const int off = (((rp * 64) + sp0 + j * 4) * 16) ^ ((rp & 7) << 4);
        bf16x8 bf = *(const bf16x8*)(tilel + off);
#pragma unroll
        for (int i = 0; i < 4; ++i)
          acc[i][j] = __builtin_amdgcn_mfma_f32_16x16x32_bf16(af[i], bf, acc[i][j], 0, 0, 0);
      }
      __builtin_amdgcn_s_barrier();
      if (ksq == 1) {
        float lp[4][4];
#pragma unroll
        for (int i = 0; i < 4; ++i)
#pragma unroll
          for (int r = 0; r < 4; ++r) lp[i][r] = 0.0f;
#pragma unroll
        for (int i = 0; i < 4; ++i)
#pragma unroll
          for (int j = 0; j < 4; ++j)
#pragma unroll
            for (int r = 0; r < 4; ++r)
              lp[i][r] = fmaf(acc[i][j][r], cnv[i][j][r], lp[i][r]);
#pragma unroll
        for (int off = 1; off < 16; off <<= 1)
#pragma unroll
          for (int i = 0; i < 4; ++i)
#pragma unroll
            for (int r = 0; r < 4; ++r) lp[i][r] += __shfl_xor(lp[i][r], off);
        float ov = lp[0][0];
#pragma unroll
        for (int i = 0; i < 4; ++i)
#pragma unroll
          for (int r = 0; r < 4; ++r)
            ov = (lr == i * 4 + r) ? lp[i][r] : ov;
        const int b = 16 * (lr >> 2) + 4 * g + (lr & 3);
        logits[(size_t)b * NM + (size_t)nn * Mq + m] = SCALE * ov;
      }
      __builtin_amdgcn_s_barrier();
    }
  }
}

extern "C" void kernel_launch(void* const* d_in, const int* in_sizes, int n_in,
                              void* d_out, int out_size, void* d_ws, size_t ws_size,
                              hipStream_t stream) {
  const float* input    = (const float*)d_in[0];
  const float* cur_act  = (const float*)d_in[1];
  const float* ncvin    = (const float*)d_in[2];
  const float* next_act = (const float*)d_in[3];
  const float* wgt      = (const float*)d_in[4];

  float* out = (float*)d_out;
  float* ncv = out;
  float* qk  = out + NCV_SZ + NA_SZ;

  // --- real path (verified r5 structure, ~161 us, produces graded output) ---
  k0_init<<<(NCV_SZ + NA_SZ + 255) / 256, 256, 0, stream>>>(out);
  k1_logits<<<dim3(32, 16), 256, 0, stream>>>(input, ncvin, wgt, qk);
  k2_softmax<<<(Bq * Nq) / 4, 256, 0, stream>>>(next_act, qk);
  k3_aggregate<<<dim3(32, 16), 256, 0, stream>>>(input, cur_act, wgt, qk, ncv);

  // --- diagnostic dispatches: scratch-only, deterministic ---
  if (ws_size >= DIAG_BYTES) {
    char*  w2       = (char*)d_ws;                             // [0, 128 MiB)
    float* logits_s = (float*)((char*)d_ws + (256u << 20));    // scratch logits
    k_conv3<<<dim3(8, Nq), 512, 0, stream>>>(wgt, w2);
    k1_dummy<<<dim3(32, 16), 256, 0, stream>>>(input, ncvin, w2, logits_s);
  }
}

// Round 11
// 153.031 us; speedup vs baseline: 2.2225x; 2.2225x over previous
//
#include <hip/hip_runtime.h>

// CapsuleFC: B=64, N=128, A=64, M=128, D=64
// out = [ncv (B*M*D) | na (B*M) | qk (B*N*M)], fp32
// R11: legacy verified math, 512-thr blocks (8 waves = 4 m-waves x 2 b-waves)
// -> 16 waves/CU to double per-CU outstanding cold-miss capacity.
typedef __attribute__((ext_vector_type(8))) short bf16x8;
typedef __attribute__((ext_vector_type(4))) float f32x4;

constexpr int Bq = 64, Nq = 128, Aq = 64, Mq = 128, Dq = 64;
constexpr int MD = Mq * Dq;    // 8192
constexpr int NM = Nq * Mq;    // 16384
constexpr int NA = Nq * Aq;    // 8192
constexpr int NCV_SZ = Bq * MD;   // 524288
constexpr int NA_SZ  = Bq * Mq;   // 8192
constexpr float SCALE = 0.125f;   // 1/sqrt(64)

__device__ __forceinline__ unsigned short f2b(float f) {  // fp32 -> bf16 RNE
  unsigned u = __float_as_uint(f);
  return (unsigned short)((u + 0x7fffu + ((u >> 16) & 1u)) >> 16);
}
__device__ __forceinline__ unsigned cvt2(float lo, float hi) {
  return ((unsigned)f2b(hi) << 16) | (unsigned)f2b(lo);
}
__device__ __forceinline__ bf16x8 pack8(const float* v) {
  union { unsigned u[4]; bf16x8 b; } x;
  x.u[0] = cvt2(v[0], v[1]); x.u[1] = cvt2(v[2], v[3]);
  x.u[2] = cvt2(v[4], v[5]); x.u[3] = cvt2(v[6], v[7]);
  return x.b;
}
__device__ __forceinline__ void dma16(const float* g, float* l) {
  __builtin_amdgcn_global_load_lds(
      (const __attribute__((address_space(1))) unsigned*)g,
      (__attribute__((address_space(3))) unsigned*)l, 16, 0, 0);
}

// ---------------- init: ncv = 0, na = 1 ----------------
__global__ __launch_bounds__(256) void k0_init(float* __restrict__ out) {
  int i = blockIdx.x * 256 + threadIdx.x;
  if (i < NCV_SZ) out[i] = 0.0f;
  else if (i < NCV_SZ + NA_SZ) out[i] = 1.0f;
}

// ---------------- K1: logits via MFMA, 8-wave blocks ----------------
// grid (mc=32, ns=16), block 512. Wave w8 = (wv_b, wv_m): m = mc*4+wv_m,
// b-range 32*wv_b..+32. Tiles walked descending (L3-cyclic with k3).
__global__ __launch_bounds__(512, 4) void k1_logits(
    const float* __restrict__ input, const float* __restrict__ ncvin,
    const float* __restrict__ wgt, float* __restrict__ logits) {
  const int mc = blockIdx.x;
  const int n0 = blockIdx.y * 8;
  const int t = threadIdx.x;
  const int w8 = t >> 6, l = t & 63;
  const int wv_m = w8 & 3, wv_b = w8 >> 2;
  const int lr = l & 15, g = l >> 4;
  const int m = mc * 4 + wv_m;
  __shared__ float Wf[2][32 * 256];   // 64 KB ring

  // preload ncvin fragment (once; epilogue is vmcnt-free)
  float cnv[2][4][4];
#pragma unroll
  for (int i = 0; i < 2; ++i)
#pragma unroll
    for (int j = 0; j < 4; ++j)
#pragma unroll
      for (int r = 0; r < 4; ++r)
        cnv[i][j][r] = ncvin[(size_t)(32 * wv_b + 16 * i + 4 * g + r) * MD + m * Dq + 16 * j + lr];

  auto stage = [&](int h) {            // descending walk
    const int hh = 15 - h;
    const int nn = n0 + (hh >> 1);
    const int ks = (hh & 1) * 32;
    float* dst = &Wf[h & 1][0];
#pragma unroll
    for (int rr = 0; rr < 4; ++rr) {   // wave stages rows w8*4..+4
      const int al = w8 * 4 + rr;
      const char* gs = (const char*)(wgt + (size_t)(nn * Aq + ks + al) * MD + mc * 256)
                       + ((l * 16) ^ (((al >> 3) & 1) << 6));
      dma16((const float*)gs, dst + al * 256);
    }
  };
  stage(0);
  f32x4 acc[2][4];

  for (int h = 0; h < 16; ++h) {
    const int hh = 15 - h;
    const int nn = n0 + (hh >> 1);
    const int ks = (hh & 1) * 32;

    float av[2][8];
#pragma unroll
    for (int i = 0; i < 2; ++i) {
      const float* ap = input + (size_t)(32 * wv_b + 16 * i + lr) * NA + nn * Aq + ks + g * 8;
      *(float4*)&av[i][0] = *(const float4*)ap;
      *(float4*)&av[i][4] = *(const float4*)(ap + 4);
    }
    __builtin_amdgcn_sched_barrier(0);

    if (h < 15) {
      stage(h + 1);
      asm volatile("s_waitcnt vmcnt(4)" ::: "memory");  // retire tile h + av; keep h+1
    } else {
      asm volatile("s_waitcnt vmcnt(0)" ::: "memory");
    }
    __builtin_amdgcn_s_barrier();

    if ((h & 1) == 0) {
#pragma unroll
      for (int i = 0; i < 2; ++i)
#pragma unroll
        for (int j = 0; j < 4; ++j) acc[i][j] = (f32x4)(0.0f);
    }

    bf16x8 af[2];
#pragma unroll
    for (int i = 0; i < 2; ++i) af[i] = pack8(av[i]);

    const float* bufp = &Wf[h & 1][0];
#pragma unroll
    for (int j = 0; j < 4; ++j) {
      const int cx = (64 * wv_m + 16 * j + lr) ^ ((g & 1) << 4);
      float bv[8];
#pragma unroll
      for (int e = 0; e < 8; ++e) bv[e] = bufp[(g * 8 + e) * 256 + cx];
      bf16x8 bf = pack8(bv);
#pragma unroll
      for (int i = 0; i < 2; ++i)
        acc[i][j] = __builtin_amdgcn_mfma_f32_16x16x32_bf16(af[i], bf, acc[i][j], 0, 0, 0);
    }
    __builtin_amdgcn_s_barrier();   // all waves done reading buf[h&1]

    if (h & 1) {
      float lp[2][4];
#pragma unroll
      for (int i = 0; i < 2; ++i)
#pragma unroll
        for (int r = 0; r < 4; ++r) lp[i][r] = 0.0f;
#pragma unroll
      for (int i = 0; i < 2; ++i)
#pragma unroll
        for (int j = 0; j < 4; ++j)
#pragma unroll
          for (int r = 0; r < 4; ++r)
            lp[i][r] = fmaf(acc[i][j][r], cnv[i][j][r], lp[i][r]);
#pragma unroll
      for (int off = 1; off < 16; off <<= 1)
#pragma unroll
        for (int i = 0; i < 2; ++i)
#pragma unroll
          for (int r = 0; r < 4; ++r) lp[i][r] += __shfl_xor(lp[i][r], off);
      // lanes lr<8 store: b = 32*wv_b + 16*(lr>>2) + 4*g + (lr&3)
      float ov = lp[0][0];
#pragma unroll
      for (int i = 0; i < 2; ++i)
#pragma unroll
        for (int r = 0; r < 4; ++r)
          ov = (lr == i * 4 + r) ? lp[i][r] : ov;
      if (lr < 8) {
        const int b = 32 * wv_b + 16 * (lr >> 2) + 4 * g + (lr & 3);
        logits[(size_t)b * NM + (size_t)nn * Mq + m] = SCALE * ov;
      }
    }
  }
}

// ---------------- K2: softmax + act modulation + renorm (in place) ----------------
__global__ __launch_bounds__(256) void k2_softmax(
    const float* __restrict__ next_act, float* __restrict__ qk) {
  const int row  = blockIdx.x * 4 + (threadIdx.x >> 6);
  const int lane = threadIdx.x & 63;
  const int b = row >> 7;
  float* p = qk + (size_t)row * Mq;
  float x0 = p[lane], x1 = p[lane + 64];
  float mx = fmaxf(x0, x1);
#pragma unroll
  for (int off = 32; off; off >>= 1) mx = fmaxf(mx, __shfl_xor(mx, off));
  float e0 = __expf(x0 - mx), e1 = __expf(x1 - mx);
  float s = e0 + e1;
#pragma unroll
  for (int off = 32; off; off >>= 1) s += __shfl_xor(s, off);
  float a0 = next_act[b * Mq + lane], a1 = next_act[b * Mq + lane + 64];
  float t0 = (e0 / s) * a0, t1 = (e1 / s) * a1;
  float s2 = t0 + t1;
#pragma unroll
  for (int off = 32; off; off >>= 1) s2 += __shfl_xor(s2, off);
  s2 += 1e-10f;
  p[lane]      = t0 / s2;
  p[lane + 64] = t1 / s2;
}

// ---------------- K3: aggregation via MFMA, 8-wave blocks (ascending walk) ----
__global__ __launch_bounds__(512, 4) void k3_aggregate(
    const float* __restrict__ input, const float* __restrict__ cur_act,
    const float* __restrict__ wgt, const float* __restrict__ qk,
    float* __restrict__ ncv) {
  const int mc = blockIdx.x;
  const int n0 = blockIdx.y * 8;
  const int t = threadIdx.x;
  const int w8 = t >> 6, l = t & 63;
  const int wv_m = w8 & 3, wv_b = w8 >> 2;
  const int lr = l & 15, g = l >> 4;
  const int m = mc * 4 + wv_m;
  __shared__ float Wf[2][32 * 256];   // 64 KB
  __shared__ float zl[8][4][64];      // 8 KB, persistent

  {  // pre-stage z = qk*cur_act, one pass of 512 threads
    const int b = t >> 3, nn = t & 7;
    float4 q4 = *(const float4*)&qk[(size_t)b * NM + (size_t)(n0 + nn) * Mq + mc * 4];
    float ca = cur_act[b * Nq + n0 + nn];
    zl[nn][0][b] = q4.x * ca; zl[nn][1][b] = q4.y * ca;
    zl[nn][2][b] = q4.z * ca; zl[nn][3][b] = q4.w * ca;
  }
  __syncthreads();

  auto stage = [&](int h) {            // ascending walk
    const int nn = n0 + (h >> 1);
    const int ks = (h & 1) * 32;
    float* dst = &Wf[h & 1][0];
#pragma unroll
    for (int rr = 0; rr < 4; ++rr) {
      const int al = w8 * 4 + rr;
      const char* gs = (const char*)(wgt + (size_t)(nn * Aq + ks + al) * MD + mc * 256)
                       + ((l * 16) ^ (((al >> 3) & 1) << 6));
      dma16((const float*)gs, dst + al * 256);
    }
  };
  stage(0);
  f32x4 acc[2][4];
#pragma unroll
  for (int i = 0; i < 2; ++i)
#pragma unroll
    for (int j = 0; j < 4; ++j) acc[i][j] = (f32x4)(0.0f);

  float zr[2];
  for (int h = 0; h < 16; ++h) {
    const int nnl = h >> 1;
    const int nn = n0 + nnl;
    const int ks = (h & 1) * 32;

    if ((h & 1) == 0) {
#pragma unroll
      for (int i = 0; i < 2; ++i) zr[i] = zl[nnl][wv_m][32 * wv_b + 16 * i + lr];
    }

    float av[2][8];
#pragma unroll
    for (int i = 0; i < 2; ++i) {
      const float* ap = input + (size_t)(32 * wv_b + 16 * i + lr) * NA + nn * Aq + ks + g * 8;
      *(float4*)&av[i][0] = *(const float4*)ap;
      *(float4*)&av[i][4] = *(const float4*)(ap + 4);
    }
    __builtin_amdgcn_sched_barrier(0);

    if (h < 15) {
      stage(h + 1);
      asm volatile("s_waitcnt vmcnt(4)" ::: "memory");
    } else {
      asm volatile("s_waitcnt vmcnt(0)" ::: "memory");
    }
    __builtin_amdgcn_s_barrier();

    bf16x8 af[2];
#pragma unroll
    for (int i = 0; i < 2; ++i) {
      float sv[8];
#pragma unroll
      for (int e = 0; e < 8; ++e) sv[e] = av[i][e] * zr[i];
      af[i] = pack8(sv);
    }

    const float* bufp = &Wf[h & 1][0];
#pragma unroll
    for (int j = 0; j < 4; ++j) {
      const int cx = (64 * wv_m + 16 * j + lr) ^ ((g & 1) << 4);
      float bv[8];
#pragma unroll
      for (int e = 0; e < 8; ++e) bv[e] = bufp[(g * 8 + e) * 256 + cx];
      bf16x8 bf = pack8(bv);
#pragma unroll
      for (int i = 0; i < 2; ++i)
        acc[i][j] = __builtin_amdgcn_mfma_f32_16x16x32_bf16(af[i], bf, acc[i][j], 0, 0, 0);
    }
    __builtin_amdgcn_s_barrier();
  }

  // epilogue: atomic partial sums over the 16 n-split blocks
#pragma unroll
  for (int i = 0; i < 2; ++i)
#pragma unroll
    for (int j = 0; j < 4; ++j) {
      const int d = 16 * j + lr;
#pragma unroll
      for (int r = 0; r < 4; ++r) {
        const int b = 32 * wv_b + 16 * i + 4 * g + r;
        atomicAdd(&ncv[(size_t)b * MD + m * Dq + d], acc[i][j][r]);
      }
    }
}

extern "C" void kernel_launch(void* const* d_in, const int* in_sizes, int n_in,
                              void* d_out, int out_size, void* d_ws, size_t ws_size,
                              hipStream_t stream) {
  const float* input    = (const float*)d_in[0];
  const float* cur_act  = (const float*)d_in[1];
  const float* ncvin    = (const float*)d_in[2];
  const float* next_act = (const float*)d_in[3];
  const float* wgt      = (const float*)d_in[4];
  // d_in[5] = num_iter (unused by reference)

  float* out = (float*)d_out;
  float* ncv = out;
  float* qk  = out + NCV_SZ + NA_SZ;

  k0_init<<<(NCV_SZ + NA_SZ + 255) / 256, 256, 0, stream>>>(out);
  k1_logits<<<dim3(32, 16), 512, 0, stream>>>(input, ncvin, wgt, qk);
  k2_softmax<<<(Bq * Nq) / 4, 256, 0, stream>>>(next_act, qk);
  k3_aggregate<<<dim3(32, 16), 512, 0, stream>>>(input, cur_act, wgt, qk, ncv);
}